// Round 16
// baseline (208.874 us; speedup 1.0000x reference)
//
#include <hip/hip_runtime.h>
#include <hip/hip_bf16.h>

typedef unsigned short u16;
typedef unsigned int   u32;

using bf8 = __attribute__((ext_vector_type(8))) __bf16;
using f4  = __attribute__((ext_vector_type(4))) float;

__device__ __forceinline__ float b2f(u16 u) {
    union { u32 i; float f; } v; v.i = ((u32)u) << 16; return v.f;
}
__device__ __forceinline__ u16 f2b(float f) {
    union { float f; u32 i; } v; v.f = f;
    u32 x = v.i;
    x += 0x7fffu + ((x >> 16) & 1u);   // RNE
    return (u16)(x >> 16);
}
// Packed fp32x2 -> bf16x2 (low = first arg).
__device__ __forceinline__ u32 pk2(float lo, float hi) {
    union { __hip_bfloat162 h; u32 u; } v;
    v.h = __float22bfloat162_rn(make_float2(lo, hi));
    return v.u;
}

// ---------------------------------------------------------------------------
// Weight swizzle (verified layout — unchanged; frags used as A-operands):
// dst[((kt*16+ct)*64+lane)*8+j] = bf16(W[kt*32+(lane>>4)*8+j][ct*16+(lane&15)])
// ---------------------------------------------------------------------------
__global__ void swz_all(const float* __restrict__ w1, const float* __restrict__ w3,
                        const float* __restrict__ w2, const float* __restrict__ w4,
                        const float* __restrict__ w5, const float* __restrict__ w7,
                        u16* __restrict__ ws) {
    __shared__ u16 slab[32 * 270];
    int b = blockIdx.x, t = threadIdx.x;
    const float* src; u16* dst; int kmax, kt;
    if      (b <  2) { src = w1; dst = ws;          kmax = 54;  kt = b;      }
    else if (b <  4) { src = w3; dst = ws + 16384;  kmax = 54;  kt = b - 2;  }
    else if (b < 12) { src = w2; dst = ws + 32768;  kmax = 256; kt = b - 4;  }
    else if (b < 20) { src = w4; dst = ws + 98304;  kmax = 256; kt = b - 12; }
    else if (b < 28) { src = w5; dst = ws + 163840; kmax = 256; kt = b - 20; }
    else             { src = w7; dst = ws + 229376; kmax = 256; kt = b - 28; }

    #pragma unroll
    for (int it = 0; it < 8; ++it) {
        int flat = it * 1024 + t * 4;
        int row = flat >> 8, col = flat & 255;
        int k = kt * 32 + row;
        float4 v = make_float4(0.f, 0.f, 0.f, 0.f);
        if (k < kmax) v = *(const float4*)(src + k * 256 + col);
        u32* sp = (u32*)&slab[row * 270 + col];
        sp[0] = pk2(v.x, v.y);
        sp[1] = pk2(v.z, v.w);
    }
    __syncthreads();

    int lane = t & 63, wave = t >> 6, lr = lane & 15, kg = lane >> 4;
    #pragma unroll
    for (int i = 0; i < 4; ++i) {
        int ct = wave * 4 + i;
        u16 v[8];
        #pragma unroll
        for (int j = 0; j < 8; ++j)
            v[j] = slab[(kg * 8 + j) * 270 + ct * 16 + lr];
        uint4 o;
        o.x = (u32)v[0] | ((u32)v[1] << 16);
        o.y = (u32)v[2] | ((u32)v[3] << 16);
        o.z = (u32)v[4] | ((u32)v[5] << 16);
        o.w = (u32)v[6] | ((u32)v[7] << 16);
        *(uint4*)(dst + (size_t)(((kt * 16 + ct) * 64 + lane) * 8)) = o;
    }
}

// ---------------------------------------------------------------------------
// Fused critic. R15 post-mortem: all pipes <50%, Occ 40% -> bound by the
// serial phase chain with only 2 independent blocks/CU. THIS round:
// batch-16 blocks, 256 thr / 4 waves (wave = wc = column-tile), LDS
// 38912 B -> 4 blocks/CU = 4 independent barrier domains (same 4
// waves/SIMD). Per-wave inner-loop shape identical to the proven R15
// kernel (acc[3][4], unroll 1, SB early-evict, fused final dot) -> no new
// spill risk. Rho handles both nets per wave (ns loop replaces wr).
//
// LDS layout (u16), activation rows XOR-swizzled:
//   physical = row*stride + (logical_col ^ ((row&7)<<3))
//   inp: rows 0..47, stride 64  ([0, 3072))   (dead by rho -> f32 scratch)
//   h  : rows 0..47, stride 256 ([3072, 15360)); S2 -> dead h rows 16..31
//   SB : rows 0..15, stride 256 ([15360, 19456))  <- S1 early-evict
// Total 38912 B -> 4 blocks/CU (155648 <= 163840), 16 waves/CU.
// ---------------------------------------------------------------------------
#define H_OFF 3072
#define S2O   (16 * 256)
#define SBO   (H_OFF + 48 * 256)

__global__ __launch_bounds__(256) __attribute__((amdgpu_waves_per_eu(4, 4)))
void critic_kernel(
    const float* __restrict__ obs, const float* __restrict__ ag,
    const float* __restrict__ g,   const float* __restrict__ anchor,
    const float* __restrict__ act,
    const float* __restrict__ b1,  const float* __restrict__ b2,
    const float* __restrict__ b3,  const float* __restrict__ b4,
    const float* __restrict__ b5,  const float* __restrict__ b7,
    const float* __restrict__ w6,  const float* __restrict__ b6,
    const float* __restrict__ w8,  const float* __restrict__ b8,
    const u16* __restrict__ wsz, float* __restrict__ out, int B) {

    __shared__ u16 pool[SBO + 16 * 256];   // 19456 u16 = 38912 B

    const int t    = threadIdx.x;
    const int lane = t & 63;
    const int wc   = t >> 6;     // 0..3 : column-tile (ct = wc*4+c)
    const int lr   = lane & 15;
    const int lg   = lane >> 4;
    const int wg   = blockIdx.x;
    const int swr  = (lr & 7) << 3;   // row-XOR swizzle (rows are p*16+lr)

    // ---- Gather: build pair inputs (48 rows x 54, pad to 64), swizzled.
    // 2 threads/row: part 0 -> cols [0,32), part 1 -> cols [32,64).
    if (t < 96) {
        const int O1[3] = {0, 0, 1}, O2[3] = {1, 2, 2};
        const int JA[3] = {3, 4, 6}, KA[3] = {5, 7, 8};
        int rr = t >> 1, part = t & 1;
        int p = rr >> 4, bl = rr & 15;
        int b = wg * 16 + bl;
        int j = JA[p], k = KA[p];
        bool sel = (anchor[b * 9 + j] - anchor[b * 9 + k]) >= 0.0f;
        u16* row = &pool[rr * 64];
        const int sw = (rr & 7) << 3;
        const u16 ONE = 0x3F80;
        if (part == 0) {
            int bit2 = sel ? j : k;
            int oi = sel ? O1[p] : O2[p];
            row[0 ^ sw] = f2b(ag[b * 9 + p]);
            row[1 ^ sw] = f2b(ag[b * 9 + bit2]);
            row[2 ^ sw] = f2b(g[b * 9 + p]);
            row[3 ^ sw] = f2b(g[b * 9 + bit2]);
            for (int c = 0; c < 10; ++c) row[(4 + c) ^ sw] = f2b(obs[b * 55 + c]);
            row[14 ^ sw] = (oi == 0) ? ONE : 0;
            row[15 ^ sw] = (oi == 1) ? ONE : 0;
            row[16 ^ sw] = (oi == 2) ? ONE : 0;
            for (int c = 0; c < 15; ++c) row[(17 + c) ^ sw] = f2b(obs[b * 55 + 10 + 15 * oi + c]);
        } else {
            int oj = sel ? O2[p] : O1[p];
            row[32 ^ sw] = (oj == 0) ? ONE : 0;
            row[33 ^ sw] = (oj == 1) ? ONE : 0;
            row[34 ^ sw] = (oj == 2) ? ONE : 0;
            for (int c = 0; c < 15; ++c) row[(35 + c) ^ sw] = f2b(obs[b * 55 + 10 + 15 * oj + c]);
            for (int c = 0; c < 4; ++c)  row[(50 + c) ^ sw] = f2b(act[b * 4 + c]);
            for (int c = 54; c < 64; ++c) row[c ^ sw] = 0;
        }
    }
    __syncthreads();

    u32 s2w[4][2];    // net1 pair-sums (brief: epilogue -> post-barrier write)

    // ---- Phi networks (net 0: w1/w2, net 1: w3/w4) ----
    for (int net = 0; net < 2; ++net) {
        const u16* Wl1 = wsz + (net ? 16384 : 0);
        const u16* Wl2 = wsz + 32768 + (net ? 65536 : 0);
        const float* bl1 = net ? b3 : b1;
        const float* bl2 = net ? b4 : b2;

        // Layer 1: A=W1^T frags, B=inp rows p*16+lr. D=(batch=lr, hid=lg*4+reg)
        f4 acc[3][4];
        #pragma unroll
        for (int p = 0; p < 3; ++p)
            #pragma unroll
            for (int c = 0; c < 4; ++c) acc[p][c] = (f4){0.f, 0.f, 0.f, 0.f};
        __builtin_amdgcn_s_setprio(1);
        #pragma unroll 1
        for (int kt = 0; kt < 2; ++kt) {
            bf8 wfr[4];
            #pragma unroll
            for (int c = 0; c < 4; ++c)
                wfr[c] = *(const bf8*)(Wl1 + (size_t)(((kt * 16 + wc * 4 + c) * 64 + lane) * 8));
            #pragma unroll
            for (int p = 0; p < 3; ++p) {
                bf8 xfr = *(const bf8*)(&pool[(p * 16 + lr) * 64 + ((kt * 32 + lg * 8) ^ swr)]);
                #pragma unroll
                for (int c = 0; c < 4; ++c)
                    acc[p][c] = __builtin_amdgcn_mfma_f32_16x16x32_bf16(wfr[c], xfr, acc[p][c], 0, 0, 0);
            }
        }
        __builtin_amdgcn_s_setprio(0);
        #pragma unroll
        for (int c = 0; c < 4; ++c) {
            float4 bv = *(const float4*)(bl1 + (wc * 4 + c) * 16 + lg * 4);
            #pragma unroll
            for (int p = 0; p < 3; ++p) {
                uint2 w;
                w.x = pk2(fmaxf(acc[p][c][0] + bv.x, 0.f), fmaxf(acc[p][c][1] + bv.y, 0.f));
                w.y = pk2(fmaxf(acc[p][c][2] + bv.z, 0.f), fmaxf(acc[p][c][3] + bv.w, 0.f));
                *(uint2*)&pool[H_OFF + (p * 16 + lr) * 256 + ((((wc * 4 + c) * 16) + lg * 4) ^ swr)] = w;
            }
        }
        __syncthreads();

        // Layer 2: A=W2^T frags, B=h rows p*16+lr. Relu + in-register pair-sum.
        f4 acc2[3][4];
        #pragma unroll
        for (int p = 0; p < 3; ++p)
            #pragma unroll
            for (int c = 0; c < 4; ++c) acc2[p][c] = (f4){0.f, 0.f, 0.f, 0.f};
        __builtin_amdgcn_s_setprio(1);
        #pragma unroll 1
        for (int ks = 0; ks < 8; ++ks) {
            bf8 wfr[4];
            #pragma unroll
            for (int c = 0; c < 4; ++c)
                wfr[c] = *(const bf8*)(Wl2 + (size_t)(((ks * 16 + wc * 4 + c) * 64 + lane) * 8));
            #pragma unroll
            for (int p = 0; p < 3; ++p) {
                bf8 hfr = *(const bf8*)(&pool[H_OFF + (p * 16 + lr) * 256 + ((ks * 32 + lg * 8) ^ swr)]);
                #pragma unroll
                for (int c = 0; c < 4; ++c)
                    acc2[p][c] = __builtin_amdgcn_mfma_f32_16x16x32_bf16(wfr[c], hfr, acc2[p][c], 0, 0, 0);
            }
        }
        __builtin_amdgcn_s_setprio(0);
        #pragma unroll
        for (int c = 0; c < 4; ++c) {
            float4 bv = *(const float4*)(bl2 + (wc * 4 + c) * 16 + lg * 4);
            f4 sv = (f4){0.f, 0.f, 0.f, 0.f};
            #pragma unroll
            for (int p = 0; p < 3; ++p) {
                sv[0] += fmaxf(acc2[p][c][0] + bv.x, 0.f);
                sv[1] += fmaxf(acc2[p][c][1] + bv.y, 0.f);
                sv[2] += fmaxf(acc2[p][c][2] + bv.z, 0.f);
                sv[3] += fmaxf(acc2[p][c][3] + bv.w, 0.f);
            }
            if (net == 0) {
                // S1 early-evict: write straight to the dedicated SB region
                // (disjoint from h -> no race with other waves' h reads).
                uint2 w;
                w.x = pk2(sv[0], sv[1]);
                w.y = pk2(sv[2], sv[3]);
                *(uint2*)&pool[SBO + lr * 256 + ((((wc * 4 + c) * 16) + lg * 4) ^ swr)] = w;
            } else {
                s2w[c][0] = pk2(sv[0], sv[1]);
                s2w[c][1] = pk2(sv[2], sv[3]);
            }
        }
        __syncthreads();  // h reads done before next net overwrites h / S2 write
    }

    // ---- Write S2 into dead h rows 16..31 (all h reads completed) ----
    #pragma unroll
    for (int c = 0; c < 4; ++c) {
        int base = H_OFF + S2O + lr * 256 + ((((wc * 4 + c) * 16) + lg * 4) ^ swr);
        *(uint2*)&pool[base] = *(uint2*)&s2w[c][0];
    }
    __syncthreads();

    // ---- Rho hidden layer + FUSED final dot; each wave does BOTH nets ----
    // ns=0: S1@SB / W5 / b5 / w6;  ns=1: S2 / W7 / b7 / w8.
    {
        const u16* W5 = wsz + 163840;
        const u16* W7 = wsz + 229376;
        f4 racc[2][4];
        #pragma unroll
        for (int ns = 0; ns < 2; ++ns)
            #pragma unroll
            for (int c = 0; c < 4; ++c) racc[ns][c] = (f4){0.f, 0.f, 0.f, 0.f};
        __builtin_amdgcn_s_setprio(1);
        #pragma unroll 1
        for (int ks = 0; ks < 8; ++ks) {
            #pragma unroll
            for (int ns = 0; ns < 2; ++ns) {
                const u16* Wr = ns ? W7 : W5;
                const int sbase = ns ? (H_OFF + S2O) : SBO;
                bf8 wf[4];
                #pragma unroll
                for (int c = 0; c < 4; ++c)
                    wf[c] = *(const bf8*)(Wr + (size_t)(((ks * 16 + wc * 4 + c) * 64 + lane) * 8));
                bf8 sf = *(const bf8*)(&pool[sbase + lr * 256 + ((ks * 32 + lg * 8) ^ swr)]);
                #pragma unroll
                for (int c = 0; c < 4; ++c)
                    racc[ns][c] = __builtin_amdgcn_mfma_f32_16x16x32_bf16(wf[c], sf, racc[ns][c], 0, 0, 0);
            }
        }
        __builtin_amdgcn_s_setprio(0);
        // Fused epilogue: q-partial = sum_h relu(racc + b) * wq[h], f32.
        // Lane holds hidden units (wc*4+c)*16+lg*4+i for batch lr.
        float part[2] = {0.f, 0.f};
        #pragma unroll
        for (int ns = 0; ns < 2; ++ns) {
            const float* br = ns ? b7 : b5;
            const float* wq = ns ? w8 : w6;
            #pragma unroll
            for (int c = 0; c < 4; ++c) {
                float4 bv = *(const float4*)(br + (wc * 4 + c) * 16 + lg * 4);
                float4 wv = *(const float4*)(wq + (wc * 4 + c) * 16 + lg * 4);
                part[ns] += fmaxf(racc[ns][c][0] + bv.x, 0.f) * wv.x
                          + fmaxf(racc[ns][c][1] + bv.y, 0.f) * wv.y
                          + fmaxf(racc[ns][c][2] + bv.z, 0.f) * wv.z
                          + fmaxf(racc[ns][c][3] + bv.w, 0.f) * wv.w;
            }
        }
        // Reduce over the 4 lg quads (lane bits 4,5); all lanes same-lr equal.
        #pragma unroll
        for (int ns = 0; ns < 2; ++ns) {
            part[ns] += __shfl_xor(part[ns], 16);
            part[ns] += __shfl_xor(part[ns], 32);
        }
        // One f32 partial per (net, batch, wc) into the dead inp region.
        if (lane < 16) {
            float* fs = (float*)pool;
            fs[(0 * 16 + lane) * 4 + wc]  = part[0];
            fs[(1 * 16 + lane) * 4 + wc]  = part[1];
        }
        __syncthreads();
    }

    // ---- Final reduce: 32 threads sum the 4 wc partials. FP32 OUT ----
    if (t < 32) {
        int net = t >> 4, b = t & 15;
        const float* fs = (const float*)pool;
        float qv = net ? b8[0] : b6[0];
        #pragma unroll
        for (int p = 0; p < 4; ++p)
            qv += fs[(net * 16 + b) * 4 + p];
        out[net * B + wg * 16 + b] = qv;
    }
}

extern "C" void kernel_launch(void* const* d_in, const int* in_sizes, int n_in,
                              void* d_out, int out_size, void* d_ws, size_t ws_size,
                              hipStream_t stream) {
    const float* obs = (const float*)d_in[0];
    const float* ag  = (const float*)d_in[1];
    const float* g   = (const float*)d_in[2];
    const float* anc = (const float*)d_in[3];
    const float* act = (const float*)d_in[4];
    const float* w1  = (const float*)d_in[5];
    const float* b1  = (const float*)d_in[6];
    const float* w2  = (const float*)d_in[7];
    const float* b2  = (const float*)d_in[8];
    const float* w3  = (const float*)d_in[9];
    const float* b3  = (const float*)d_in[10];
    const float* w4  = (const float*)d_in[11];
    const float* b4  = (const float*)d_in[12];
    const float* w5  = (const float*)d_in[13];
    const float* b5  = (const float*)d_in[14];
    const float* w6  = (const float*)d_in[15];
    const float* b6  = (const float*)d_in[16];
    const float* w7  = (const float*)d_in[17];
    const float* b7  = (const float*)d_in[18];
    const float* w8  = (const float*)d_in[19];
    const float* b8  = (const float*)d_in[20];
    u16* ws    = (u16*)d_ws;
    float* out = (float*)d_out;
    int B = in_sizes[0] / 55;

    swz_all<<<36, 256, 0, stream>>>(w1, w3, w2, w4, w5, w7, ws);
    critic_kernel<<<(B + 15) / 16, 256, 0, stream>>>(obs, ag, g, anc, act,
                                                     b1, b2, b3, b4, b5, b7,
                                                     w6, b6, w8, b8, ws, out, B);
}

// Round 18
// 195.032 us; speedup vs baseline: 1.0710x; 1.0710x over previous
//
#include <hip/hip_runtime.h>
#include <hip/hip_bf16.h>

typedef unsigned short u16;
typedef unsigned int   u32;

using bf8 = __attribute__((ext_vector_type(8))) __bf16;
using f4  = __attribute__((ext_vector_type(4))) float;

__device__ __forceinline__ float b2f(u16 u) {
    union { u32 i; float f; } v; v.i = ((u32)u) << 16; return v.f;
}
__device__ __forceinline__ u16 f2b(float f) {
    union { float f; u32 i; } v; v.f = f;
    u32 x = v.i;
    x += 0x7fffu + ((x >> 16) & 1u);   // RNE
    return (u16)(x >> 16);
}
// Packed fp32x2 -> bf16x2 (low = first arg).
__device__ __forceinline__ u32 pk2(float lo, float hi) {
    union { __hip_bfloat162 h; u32 u; } v;
    v.h = __float22bfloat162_rn(make_float2(lo, hi));
    return v.u;
}

// ---------------------------------------------------------------------------
// Weight swizzle (verified layout — unchanged; frags used as A-operands):
// dst[((kt*16+ct)*64+lane)*8+j] = bf16(W[kt*32+(lane>>4)*8+j][ct*16+(lane&15)])
// ---------------------------------------------------------------------------
__global__ void swz_all(const float* __restrict__ w1, const float* __restrict__ w3,
                        const float* __restrict__ w2, const float* __restrict__ w4,
                        const float* __restrict__ w5, const float* __restrict__ w7,
                        u16* __restrict__ ws) {
    __shared__ u16 slab[32 * 270];
    int b = blockIdx.x, t = threadIdx.x;
    const float* src; u16* dst; int kmax, kt;
    if      (b <  2) { src = w1; dst = ws;          kmax = 54;  kt = b;      }
    else if (b <  4) { src = w3; dst = ws + 16384;  kmax = 54;  kt = b - 2;  }
    else if (b < 12) { src = w2; dst = ws + 32768;  kmax = 256; kt = b - 4;  }
    else if (b < 20) { src = w4; dst = ws + 98304;  kmax = 256; kt = b - 12; }
    else if (b < 28) { src = w5; dst = ws + 163840; kmax = 256; kt = b - 20; }
    else             { src = w7; dst = ws + 229376; kmax = 256; kt = b - 28; }

    #pragma unroll
    for (int it = 0; it < 8; ++it) {
        int flat = it * 1024 + t * 4;
        int row = flat >> 8, col = flat & 255;
        int k = kt * 32 + row;
        float4 v = make_float4(0.f, 0.f, 0.f, 0.f);
        if (k < kmax) v = *(const float4*)(src + k * 256 + col);
        u32* sp = (u32*)&slab[row * 270 + col];
        sp[0] = pk2(v.x, v.y);
        sp[1] = pk2(v.z, v.w);
    }
    __syncthreads();

    int lane = t & 63, wave = t >> 6, lr = lane & 15, kg = lane >> 4;
    #pragma unroll
    for (int i = 0; i < 4; ++i) {
        int ct = wave * 4 + i;
        u16 v[8];
        #pragma unroll
        for (int j = 0; j < 8; ++j)
            v[j] = slab[(kg * 8 + j) * 270 + ct * 16 + lr];
        uint4 o;
        o.x = (u32)v[0] | ((u32)v[1] << 16);
        o.y = (u32)v[2] | ((u32)v[3] << 16);
        o.z = (u32)v[4] | ((u32)v[5] << 16);
        o.w = (u32)v[6] | ((u32)v[7] << 16);
        *(uint4*)(dst + (size_t)(((kt * 16 + ct) * 64 + lane) * 8)) = o;
    }
}

// ---------------------------------------------------------------------------
// Fused critic (R15 config — session best, restored after R16's batch-16
// regression: occupancy is waves_per_eu-capped at 16/CU, NOT block-limited,
// so smaller blocks only halved overhead amortization).
// 512 thr / 8 waves, 2-D wave split: wr = batch-half / rho net, wc = 4
// column-tiles. unroll 1 weight loops (no spill), S1 early-evict to SB,
// fused final dot in rho epilogue.
// THIS round's delta vs R15: gather spread 192 -> 384 threads (4 parts/row,
// <=16 serial loads each, halves the head-phase latency chain).
//
// LDS layout (u16), activation rows XOR-swizzled:
//   physical = row*stride + (logical_col ^ ((row&7)<<3))
//   inp: rows 0..95, stride 64  ([0, 6144))   (dead by rho -> f32 scratch)
//   h  : rows 0..95, stride 256 ([6144, 6144+24576)); S2 -> rows 32..63
//   SB : rows 0..31, stride 256 ([30720, 38912))  <- S1 early-evict region
// Total 77824 B -> 2 blocks/CU, 4 waves/SIMD.
// ---------------------------------------------------------------------------
#define H_OFF 6144
#define S2O   (32 * 256)
#define SBO   (H_OFF + 96 * 256)

__global__ __launch_bounds__(512) __attribute__((amdgpu_waves_per_eu(4, 4)))
void critic_kernel(
    const float* __restrict__ obs, const float* __restrict__ ag,
    const float* __restrict__ g,   const float* __restrict__ anchor,
    const float* __restrict__ act,
    const float* __restrict__ b1,  const float* __restrict__ b2,
    const float* __restrict__ b3,  const float* __restrict__ b4,
    const float* __restrict__ b5,  const float* __restrict__ b7,
    const float* __restrict__ w6,  const float* __restrict__ b6,
    const float* __restrict__ w8,  const float* __restrict__ b8,
    const u16* __restrict__ wsz, float* __restrict__ out, int B) {

    __shared__ u16 pool[SBO + 32 * 256];   // 38912 u16 = 77824 B

    const int t    = threadIdx.x;
    const int lane = t & 63;
    const int wave = t >> 6;     // 0..7
    const int wr   = wave >> 2;  // 0,1 : batch-lane half / rho net
    const int wc   = wave & 3;   // 0..3: 4 column-tiles
    const int lr   = lane & 15;
    const int lg   = lane >> 4;
    const int wg   = blockIdx.x;
    const int swr  = (lr & 7) << 3;   // row-XOR swizzle (h/inp rows are ..*16+lr)

    // ---- Gather: build pair inputs (96 rows x 54, pad to 64), swizzled.
    // 4 threads/row: part0 cols[0,14), part1 [14,32), part2 [32,50),
    // part3 [50,64). <=16 serial loads per thread (was ~30 at 2 parts).
    if (t < 384) {
        const int O1[3] = {0, 0, 1}, O2[3] = {1, 2, 2};
        const int JA[3] = {3, 4, 6}, KA[3] = {5, 7, 8};
        int rr = t >> 2, part = t & 3;
        int p = rr >> 5, bl = rr & 31;
        int b = wg * 32 + bl;
        int j = JA[p], k = KA[p];
        bool sel = (anchor[b * 9 + j] - anchor[b * 9 + k]) >= 0.0f;
        u16* row = &pool[rr * 64];
        const int sw = (rr & 7) << 3;
        const u16 ONE = 0x3F80;
        if (part == 0) {
            int bit2 = sel ? j : k;
            row[0 ^ sw] = f2b(ag[b * 9 + p]);
            row[1 ^ sw] = f2b(ag[b * 9 + bit2]);
            row[2 ^ sw] = f2b(g[b * 9 + p]);
            row[3 ^ sw] = f2b(g[b * 9 + bit2]);
            for (int c = 0; c < 10; ++c) row[(4 + c) ^ sw] = f2b(obs[b * 55 + c]);
        } else if (part == 1) {
            int oi = sel ? O1[p] : O2[p];
            row[14 ^ sw] = (oi == 0) ? ONE : 0;
            row[15 ^ sw] = (oi == 1) ? ONE : 0;
            row[16 ^ sw] = (oi == 2) ? ONE : 0;
            for (int c = 0; c < 15; ++c) row[(17 + c) ^ sw] = f2b(obs[b * 55 + 10 + 15 * oi + c]);
        } else if (part == 2) {
            int oj = sel ? O2[p] : O1[p];
            row[32 ^ sw] = (oj == 0) ? ONE : 0;
            row[33 ^ sw] = (oj == 1) ? ONE : 0;
            row[34 ^ sw] = (oj == 2) ? ONE : 0;
            for (int c = 0; c < 15; ++c) row[(35 + c) ^ sw] = f2b(obs[b * 55 + 10 + 15 * oj + c]);
        } else {
            for (int c = 0; c < 4; ++c)  row[(50 + c) ^ sw] = f2b(act[b * 4 + c]);
            for (int c = 54; c < 64; ++c) row[c ^ sw] = 0;
        }
    }
    __syncthreads();

    u32 s2w[4][2];    // net1 pair-sums (brief: epilogue -> post-barrier write)

    // ---- Phi networks (net 0: w1/w2, net 1: w3/w4) ----
    for (int net = 0; net < 2; ++net) {
        const u16* Wl1 = wsz + (net ? 16384 : 0);
        const u16* Wl2 = wsz + 32768 + (net ? 65536 : 0);
        const float* bl1 = net ? b3 : b1;
        const float* bl2 = net ? b4 : b2;

        // Layer 1: A=W1^T frags, B=inp rows rt=2p+wr. D=(batch=lr, hid=lg*4+reg)
        f4 acc[3][4];
        #pragma unroll
        for (int p = 0; p < 3; ++p)
            #pragma unroll
            for (int c = 0; c < 4; ++c) acc[p][c] = (f4){0.f, 0.f, 0.f, 0.f};
        __builtin_amdgcn_s_setprio(1);
        #pragma unroll 1
        for (int kt = 0; kt < 2; ++kt) {
            bf8 wfr[4];
            #pragma unroll
            for (int c = 0; c < 4; ++c)
                wfr[c] = *(const bf8*)(Wl1 + (size_t)(((kt * 16 + wc * 4 + c) * 64 + lane) * 8));
            #pragma unroll
            for (int p = 0; p < 3; ++p) {
                bf8 xfr = *(const bf8*)(&pool[((2 * p + wr) * 16 + lr) * 64 + ((kt * 32 + lg * 8) ^ swr)]);
                #pragma unroll
                for (int c = 0; c < 4; ++c)
                    acc[p][c] = __builtin_amdgcn_mfma_f32_16x16x32_bf16(wfr[c], xfr, acc[p][c], 0, 0, 0);
            }
        }
        __builtin_amdgcn_s_setprio(0);
        #pragma unroll
        for (int c = 0; c < 4; ++c) {
            float4 bv = *(const float4*)(bl1 + (wc * 4 + c) * 16 + lg * 4);
            #pragma unroll
            for (int p = 0; p < 3; ++p) {
                uint2 w;
                w.x = pk2(fmaxf(acc[p][c][0] + bv.x, 0.f), fmaxf(acc[p][c][1] + bv.y, 0.f));
                w.y = pk2(fmaxf(acc[p][c][2] + bv.z, 0.f), fmaxf(acc[p][c][3] + bv.w, 0.f));
                *(uint2*)&pool[H_OFF + ((2 * p + wr) * 16 + lr) * 256 + ((((wc * 4 + c) * 16) + lg * 4) ^ swr)] = w;
            }
        }
        __syncthreads();

        // Layer 2: A=W2^T frags, B=h rows rt=2p+wr. Relu + in-register pair-sum.
        f4 acc2[3][4];
        #pragma unroll
        for (int p = 0; p < 3; ++p)
            #pragma unroll
            for (int c = 0; c < 4; ++c) acc2[p][c] = (f4){0.f, 0.f, 0.f, 0.f};
        __builtin_amdgcn_s_setprio(1);
        #pragma unroll 1
        for (int ks = 0; ks < 8; ++ks) {
            bf8 wfr[4];
            #pragma unroll
            for (int c = 0; c < 4; ++c)
                wfr[c] = *(const bf8*)(Wl2 + (size_t)(((ks * 16 + wc * 4 + c) * 64 + lane) * 8));
            #pragma unroll
            for (int p = 0; p < 3; ++p) {
                bf8 hfr = *(const bf8*)(&pool[H_OFF + ((2 * p + wr) * 16 + lr) * 256 + ((ks * 32 + lg * 8) ^ swr)]);
                #pragma unroll
                for (int c = 0; c < 4; ++c)
                    acc2[p][c] = __builtin_amdgcn_mfma_f32_16x16x32_bf16(wfr[c], hfr, acc2[p][c], 0, 0, 0);
            }
        }
        __builtin_amdgcn_s_setprio(0);
        #pragma unroll
        for (int c = 0; c < 4; ++c) {
            float4 bv = *(const float4*)(bl2 + (wc * 4 + c) * 16 + lg * 4);
            f4 sv = (f4){0.f, 0.f, 0.f, 0.f};
            #pragma unroll
            for (int p = 0; p < 3; ++p) {
                sv[0] += fmaxf(acc2[p][c][0] + bv.x, 0.f);
                sv[1] += fmaxf(acc2[p][c][1] + bv.y, 0.f);
                sv[2] += fmaxf(acc2[p][c][2] + bv.z, 0.f);
                sv[3] += fmaxf(acc2[p][c][3] + bv.w, 0.f);
            }
            if (net == 0) {
                // S1 early-evict: write straight to the dedicated SB region
                // (disjoint from h -> no race with other waves' h reads).
                uint2 w;
                w.x = pk2(sv[0], sv[1]);
                w.y = pk2(sv[2], sv[3]);
                *(uint2*)&pool[SBO + (wr * 16 + lr) * 256 + ((((wc * 4 + c) * 16) + lg * 4) ^ swr)] = w;
            } else {
                s2w[c][0] = pk2(sv[0], sv[1]);
                s2w[c][1] = pk2(sv[2], sv[3]);
            }
        }
        __syncthreads();  // h reads done before next net overwrites h / S2 write
    }

    // ---- Write S2 into dead h rows 32..63 (all h reads completed) ----
    #pragma unroll
    for (int c = 0; c < 4; ++c) {
        int base = H_OFF + S2O + (wr * 16 + lr) * 256 + ((((wc * 4 + c) * 16) + lg * 4) ^ swr);
        *(uint2*)&pool[base] = *(uint2*)&s2w[c][0];
    }
    __syncthreads();

    // ---- Rho hidden layer + FUSED final dot ----
    // wr picks the net (wr=0: S1@SB/W5/b5/w6, wr=1: S2/W7/b7/w8).
    {
        const u16* Wr    = wsz + (wr ? 229376 : 163840);
        const int sbase  = wr ? (H_OFF + S2O) : SBO;
        const float* br  = wr ? b7 : b5;
        const float* wq  = wr ? w8 : w6;
        f4 racc[2][4];
        #pragma unroll
        for (int rt = 0; rt < 2; ++rt)
            #pragma unroll
            for (int c = 0; c < 4; ++c) racc[rt][c] = (f4){0.f, 0.f, 0.f, 0.f};
        __builtin_amdgcn_s_setprio(1);
        #pragma unroll 1
        for (int ks = 0; ks < 8; ++ks) {
            bf8 wf[4];
            #pragma unroll
            for (int c = 0; c < 4; ++c)
                wf[c] = *(const bf8*)(Wr + (size_t)(((ks * 16 + wc * 4 + c) * 64 + lane) * 8));
            #pragma unroll
            for (int rt = 0; rt < 2; ++rt) {
                bf8 sf = *(const bf8*)(&pool[sbase + (rt * 16 + lr) * 256 + ((ks * 32 + lg * 8) ^ swr)]);
                #pragma unroll
                for (int c = 0; c < 4; ++c)
                    racc[rt][c] = __builtin_amdgcn_mfma_f32_16x16x32_bf16(wf[c], sf, racc[rt][c], 0, 0, 0);
            }
        }
        __builtin_amdgcn_s_setprio(0);
        // Fused epilogue: q-partial = sum_h relu(racc + b) * wq[h], f32.
        // Lane holds hidden units (wc*4+c)*16+lg*4+i for batch rt*16+lr.
        float part[2] = {0.f, 0.f};
        #pragma unroll
        for (int c = 0; c < 4; ++c) {
            float4 bv = *(const float4*)(br + (wc * 4 + c) * 16 + lg * 4);
            float4 wv = *(const float4*)(wq + (wc * 4 + c) * 16 + lg * 4);
            #pragma unroll
            for (int rt = 0; rt < 2; ++rt) {
                part[rt] += fmaxf(racc[rt][c][0] + bv.x, 0.f) * wv.x
                          + fmaxf(racc[rt][c][1] + bv.y, 0.f) * wv.y
                          + fmaxf(racc[rt][c][2] + bv.z, 0.f) * wv.z
                          + fmaxf(racc[rt][c][3] + bv.w, 0.f) * wv.w;
            }
        }
        // Reduce over the 4 lg quads (lane bits 4,5); all lanes same-lr equal.
        #pragma unroll
        for (int rt = 0; rt < 2; ++rt) {
            part[rt] += __shfl_xor(part[rt], 16);
            part[rt] += __shfl_xor(part[rt], 32);
        }
        // One f32 partial per (net, batch, wc) into the dead inp region.
        if (lane < 16) {
            float* fs = (float*)pool;
            fs[(wr * 32 + lane) * 4 + wc]      = part[0];
            fs[(wr * 32 + 16 + lane) * 4 + wc] = part[1];
        }
        __syncthreads();
    }

    // ---- Final reduce: 64 threads sum the 4 wc partials. FP32 OUT ----
    if (t < 64) {
        int net = t >> 5, b = t & 31;
        const float* fs = (const float*)pool;
        float qv = net ? b8[0] : b6[0];
        #pragma unroll
        for (int p = 0; p < 4; ++p)
            qv += fs[(net * 32 + b) * 4 + p];
        out[net * B + wg * 32 + b] = qv;
    }
}

extern "C" void kernel_launch(void* const* d_in, const int* in_sizes, int n_in,
                              void* d_out, int out_size, void* d_ws, size_t ws_size,
                              hipStream_t stream) {
    const float* obs = (const float*)d_in[0];
    const float* ag  = (const float*)d_in[1];
    const float* g   = (const float*)d_in[2];
    const float* anc = (const float*)d_in[3];
    const float* act = (const float*)d_in[4];
    const float* w1  = (const float*)d_in[5];
    const float* b1  = (const float*)d_in[6];
    const float* w2  = (const float*)d_in[7];
    const float* b2  = (const float*)d_in[8];
    const float* w3  = (const float*)d_in[9];
    const float* b3  = (const float*)d_in[10];
    const float* w4  = (const float*)d_in[11];
    const float* b4  = (const float*)d_in[12];
    const float* w5  = (const float*)d_in[13];
    const float* b5  = (const float*)d_in[14];
    const float* w6  = (const float*)d_in[15];
    const float* b6  = (const float*)d_in[16];
    const float* w7  = (const float*)d_in[17];
    const float* b7  = (const float*)d_in[18];
    const float* w8  = (const float*)d_in[19];
    const float* b8  = (const float*)d_in[20];
    u16* ws    = (u16*)d_ws;
    float* out = (float*)d_out;
    int B = in_sizes[0] / 55;

    swz_all<<<36, 256, 0, stream>>>(w1, w3, w2, w4, w5, w7, ws);
    critic_kernel<<<(B + 31) / 32, 512, 0, stream>>>(obs, ag, g, anc, act,
                                                     b1, b2, b3, b4, b5, b7,
                                                     w6, b6, w8, b8, ws, out, B);
}

// Round 20
// 193.907 us; speedup vs baseline: 1.0772x; 1.0058x over previous
//
#include <hip/hip_runtime.h>
#include <hip/hip_bf16.h>

typedef unsigned short u16;
typedef unsigned int   u32;

using bf8 = __attribute__((ext_vector_type(8))) __bf16;
using f4  = __attribute__((ext_vector_type(4))) float;

__device__ __forceinline__ float b2f(u16 u) {
    union { u32 i; float f; } v; v.i = ((u32)u) << 16; return v.f;
}
__device__ __forceinline__ u16 f2b(float f) {
    union { float f; u32 i; } v; v.f = f;
    u32 x = v.i;
    x += 0x7fffu + ((x >> 16) & 1u);   // RNE
    return (u16)(x >> 16);
}
// Packed fp32x2 -> bf16x2 (low = first arg).
__device__ __forceinline__ u32 pk2(float lo, float hi) {
    union { __hip_bfloat162 h; u32 u; } v;
    v.h = __float22bfloat162_rn(make_float2(lo, hi));
    return v.u;
}

// ---------------------------------------------------------------------------
// Weight swizzle (verified layout — unchanged; frags used as A-operands):
// dst[((kt*16+ct)*64+lane)*8+j] = bf16(W[kt*32+(lane>>4)*8+j][ct*16+(lane&15)])
// ---------------------------------------------------------------------------
__global__ void swz_all(const float* __restrict__ w1, const float* __restrict__ w3,
                        const float* __restrict__ w2, const float* __restrict__ w4,
                        const float* __restrict__ w5, const float* __restrict__ w7,
                        u16* __restrict__ ws) {
    __shared__ u16 slab[32 * 270];
    int b = blockIdx.x, t = threadIdx.x;
    const float* src; u16* dst; int kmax, kt;
    if      (b <  2) { src = w1; dst = ws;          kmax = 54;  kt = b;      }
    else if (b <  4) { src = w3; dst = ws + 16384;  kmax = 54;  kt = b - 2;  }
    else if (b < 12) { src = w2; dst = ws + 32768;  kmax = 256; kt = b - 4;  }
    else if (b < 20) { src = w4; dst = ws + 98304;  kmax = 256; kt = b - 12; }
    else if (b < 28) { src = w5; dst = ws + 163840; kmax = 256; kt = b - 20; }
    else             { src = w7; dst = ws + 229376; kmax = 256; kt = b - 28; }

    #pragma unroll
    for (int it = 0; it < 8; ++it) {
        int flat = it * 1024 + t * 4;
        int row = flat >> 8, col = flat & 255;
        int k = kt * 32 + row;
        float4 v = make_float4(0.f, 0.f, 0.f, 0.f);
        if (k < kmax) v = *(const float4*)(src + k * 256 + col);
        u32* sp = (u32*)&slab[row * 270 + col];
        sp[0] = pk2(v.x, v.y);
        sp[1] = pk2(v.z, v.w);
    }
    __syncthreads();

    int lane = t & 63, wave = t >> 6, lr = lane & 15, kg = lane >> 4;
    #pragma unroll
    for (int i = 0; i < 4; ++i) {
        int ct = wave * 4 + i;
        u16 v[8];
        #pragma unroll
        for (int j = 0; j < 8; ++j)
            v[j] = slab[(kg * 8 + j) * 270 + ct * 16 + lr];
        uint4 o;
        o.x = (u32)v[0] | ((u32)v[1] << 16);
        o.y = (u32)v[2] | ((u32)v[3] << 16);
        o.z = (u32)v[4] | ((u32)v[5] << 16);
        o.w = (u32)v[6] | ((u32)v[7] << 16);
        *(uint4*)(dst + (size_t)(((kt * 16 + ct) * 64 + lane) * 8)) = o;
    }
}

// ---------------------------------------------------------------------------
// Fused critic (R15 structure — session best at ~107 us steady).
// 512 thr / 8 waves, 2-D wave split: wr = batch-half / rho net, wc = 4
// column-tiles. unroll 1 weight loops (no spill), S1 early-evict to SB,
// fused final dot in rho epilogue.
//
// R18 post-mortem: 4-part interleaved gather REGRESSED +7us — part=t&3
// put all 4 branch bodies in every wave (exec-mask serialization, ~50
// load-issues/wave vs 33). Implies gather head ~ 15us of steady state.
// THIS round: 2 parts/row (R15 memory layout) but parts mapped to
// CONTIGUOUS thread ranges: t<96 part0, 96<=t<192 part1 -> waves 0 and 2
// run a single branch body; only wave 1 diverges. Avg bodies/wave
// 2.0 -> ~1.33, cutting ~1/3 of the gather serialization.
//
// LDS layout (u16), activation rows XOR-swizzled:
//   physical = row*stride + (logical_col ^ ((row&7)<<3))
//   inp: rows 0..95, stride 64  ([0, 6144))   (dead by rho -> f32 scratch)
//   h  : rows 0..95, stride 256 ([6144, 6144+24576)); S2 -> rows 32..63
//   SB : rows 0..31, stride 256 ([30720, 38912))  <- S1 early-evict region
// Total 77824 B -> 2 blocks/CU, 4 waves/SIMD.
// ---------------------------------------------------------------------------
#define H_OFF 6144
#define S2O   (32 * 256)
#define SBO   (H_OFF + 96 * 256)

__global__ __launch_bounds__(512) __attribute__((amdgpu_waves_per_eu(4, 4)))
void critic_kernel(
    const float* __restrict__ obs, const float* __restrict__ ag,
    const float* __restrict__ g,   const float* __restrict__ anchor,
    const float* __restrict__ act,
    const float* __restrict__ b1,  const float* __restrict__ b2,
    const float* __restrict__ b3,  const float* __restrict__ b4,
    const float* __restrict__ b5,  const float* __restrict__ b7,
    const float* __restrict__ w6,  const float* __restrict__ b6,
    const float* __restrict__ w8,  const float* __restrict__ b8,
    const u16* __restrict__ wsz, float* __restrict__ out, int B) {

    __shared__ u16 pool[SBO + 32 * 256];   // 38912 u16 = 77824 B

    const int t    = threadIdx.x;
    const int lane = t & 63;
    const int wave = t >> 6;     // 0..7
    const int wr   = wave >> 2;  // 0,1 : batch-lane half / rho net
    const int wc   = wave & 3;   // 0..3: 4 column-tiles
    const int lr   = lane & 15;
    const int lg   = lane >> 4;
    const int wg   = blockIdx.x;
    const int swr  = (lr & 7) << 3;   // row-XOR swizzle (h/inp rows are ..*16+lr)

    // ---- Gather: build pair inputs (96 rows x 54, pad to 64), swizzled.
    // 2 parts/row in CONTIGUOUS thread ranges: t<96 -> part0 of row t,
    // 96<=t<192 -> part1 of row t-96. Waves 0,2 uniform; only wave 1 mixed.
    if (t < 192) {
        const int O1[3] = {0, 0, 1}, O2[3] = {1, 2, 2};
        const int JA[3] = {3, 4, 6}, KA[3] = {5, 7, 8};
        int part = (t >= 96) ? 1 : 0;
        int rr = part ? (t - 96) : t;
        int p = rr >> 5, bl = rr & 31;
        int b = wg * 32 + bl;
        int j = JA[p], k = KA[p];
        bool sel = (anchor[b * 9 + j] - anchor[b * 9 + k]) >= 0.0f;
        u16* row = &pool[rr * 64];
        const int sw = (rr & 7) << 3;
        const u16 ONE = 0x3F80;
        if (part == 0) {
            int bit2 = sel ? j : k;
            int oi = sel ? O1[p] : O2[p];
            row[0 ^ sw] = f2b(ag[b * 9 + p]);
            row[1 ^ sw] = f2b(ag[b * 9 + bit2]);
            row[2 ^ sw] = f2b(g[b * 9 + p]);
            row[3 ^ sw] = f2b(g[b * 9 + bit2]);
            for (int c = 0; c < 10; ++c) row[(4 + c) ^ sw] = f2b(obs[b * 55 + c]);
            row[14 ^ sw] = (oi == 0) ? ONE : 0;
            row[15 ^ sw] = (oi == 1) ? ONE : 0;
            row[16 ^ sw] = (oi == 2) ? ONE : 0;
            for (int c = 0; c < 15; ++c) row[(17 + c) ^ sw] = f2b(obs[b * 55 + 10 + 15 * oi + c]);
        } else {
            int oj = sel ? O2[p] : O1[p];
            row[32 ^ sw] = (oj == 0) ? ONE : 0;
            row[33 ^ sw] = (oj == 1) ? ONE : 0;
            row[34 ^ sw] = (oj == 2) ? ONE : 0;
            for (int c = 0; c < 15; ++c) row[(35 + c) ^ sw] = f2b(obs[b * 55 + 10 + 15 * oj + c]);
            for (int c = 0; c < 4; ++c)  row[(50 + c) ^ sw] = f2b(act[b * 4 + c]);
            for (int c = 54; c < 64; ++c) row[c ^ sw] = 0;
        }
    }
    __syncthreads();

    u32 s2w[4][2];    // net1 pair-sums (brief: epilogue -> post-barrier write)

    // ---- Phi networks (net 0: w1/w2, net 1: w3/w4) ----
    for (int net = 0; net < 2; ++net) {
        const u16* Wl1 = wsz + (net ? 16384 : 0);
        const u16* Wl2 = wsz + 32768 + (net ? 65536 : 0);
        const float* bl1 = net ? b3 : b1;
        const float* bl2 = net ? b4 : b2;

        // Layer 1: A=W1^T frags, B=inp rows rt=2p+wr. D=(batch=lr, hid=lg*4+reg)
        f4 acc[3][4];
        #pragma unroll
        for (int p = 0; p < 3; ++p)
            #pragma unroll
            for (int c = 0; c < 4; ++c) acc[p][c] = (f4){0.f, 0.f, 0.f, 0.f};
        __builtin_amdgcn_s_setprio(1);
        #pragma unroll 1
        for (int kt = 0; kt < 2; ++kt) {
            bf8 wfr[4];
            #pragma unroll
            for (int c = 0; c < 4; ++c)
                wfr[c] = *(const bf8*)(Wl1 + (size_t)(((kt * 16 + wc * 4 + c) * 64 + lane) * 8));
            #pragma unroll
            for (int p = 0; p < 3; ++p) {
                bf8 xfr = *(const bf8*)(&pool[((2 * p + wr) * 16 + lr) * 64 + ((kt * 32 + lg * 8) ^ swr)]);
                #pragma unroll
                for (int c = 0; c < 4; ++c)
                    acc[p][c] = __builtin_amdgcn_mfma_f32_16x16x32_bf16(wfr[c], xfr, acc[p][c], 0, 0, 0);
            }
        }
        __builtin_amdgcn_s_setprio(0);
        #pragma unroll
        for (int c = 0; c < 4; ++c) {
            float4 bv = *(const float4*)(bl1 + (wc * 4 + c) * 16 + lg * 4);
            #pragma unroll
            for (int p = 0; p < 3; ++p) {
                uint2 w;
                w.x = pk2(fmaxf(acc[p][c][0] + bv.x, 0.f), fmaxf(acc[p][c][1] + bv.y, 0.f));
                w.y = pk2(fmaxf(acc[p][c][2] + bv.z, 0.f), fmaxf(acc[p][c][3] + bv.w, 0.f));
                *(uint2*)&pool[H_OFF + ((2 * p + wr) * 16 + lr) * 256 + ((((wc * 4 + c) * 16) + lg * 4) ^ swr)] = w;
            }
        }
        __syncthreads();

        // Layer 2: A=W2^T frags, B=h rows rt=2p+wr. Relu + in-register pair-sum.
        f4 acc2[3][4];
        #pragma unroll
        for (int p = 0; p < 3; ++p)
            #pragma unroll
            for (int c = 0; c < 4; ++c) acc2[p][c] = (f4){0.f, 0.f, 0.f, 0.f};
        __builtin_amdgcn_s_setprio(1);
        #pragma unroll 1
        for (int ks = 0; ks < 8; ++ks) {
            bf8 wfr[4];
            #pragma unroll
            for (int c = 0; c < 4; ++c)
                wfr[c] = *(const bf8*)(Wl2 + (size_t)(((ks * 16 + wc * 4 + c) * 64 + lane) * 8));
            #pragma unroll
            for (int p = 0; p < 3; ++p) {
                bf8 hfr = *(const bf8*)(&pool[H_OFF + ((2 * p + wr) * 16 + lr) * 256 + ((ks * 32 + lg * 8) ^ swr)]);
                #pragma unroll
                for (int c = 0; c < 4; ++c)
                    acc2[p][c] = __builtin_amdgcn_mfma_f32_16x16x32_bf16(wfr[c], hfr, acc2[p][c], 0, 0, 0);
            }
        }
        __builtin_amdgcn_s_setprio(0);
        #pragma unroll
        for (int c = 0; c < 4; ++c) {
            float4 bv = *(const float4*)(bl2 + (wc * 4 + c) * 16 + lg * 4);
            f4 sv = (f4){0.f, 0.f, 0.f, 0.f};
            #pragma unroll
            for (int p = 0; p < 3; ++p) {
                sv[0] += fmaxf(acc2[p][c][0] + bv.x, 0.f);
                sv[1] += fmaxf(acc2[p][c][1] + bv.y, 0.f);
                sv[2] += fmaxf(acc2[p][c][2] + bv.z, 0.f);
                sv[3] += fmaxf(acc2[p][c][3] + bv.w, 0.f);
            }
            if (net == 0) {
                // S1 early-evict: write straight to the dedicated SB region
                // (disjoint from h -> no race with other waves' h reads).
                uint2 w;
                w.x = pk2(sv[0], sv[1]);
                w.y = pk2(sv[2], sv[3]);
                *(uint2*)&pool[SBO + (wr * 16 + lr) * 256 + ((((wc * 4 + c) * 16) + lg * 4) ^ swr)] = w;
            } else {
                s2w[c][0] = pk2(sv[0], sv[1]);
                s2w[c][1] = pk2(sv[2], sv[3]);
            }
        }
        __syncthreads();  // h reads done before next net overwrites h / S2 write
    }

    // ---- Write S2 into dead h rows 32..63 (all h reads completed) ----
    #pragma unroll
    for (int c = 0; c < 4; ++c) {
        int base = H_OFF + S2O + (wr * 16 + lr) * 256 + ((((wc * 4 + c) * 16) + lg * 4) ^ swr);
        *(uint2*)&pool[base] = *(uint2*)&s2w[c][0];
    }
    __syncthreads();

    // ---- Rho hidden layer + FUSED final dot ----
    // wr picks the net (wr=0: S1@SB/W5/b5/w6, wr=1: S2/W7/b7/w8).
    {
        const u16* Wr    = wsz + (wr ? 229376 : 163840);
        const int sbase  = wr ? (H_OFF + S2O) : SBO;
        const float* br  = wr ? b7 : b5;
        const float* wq  = wr ? w8 : w6;
        f4 racc[2][4];
        #pragma unroll
        for (int rt = 0; rt < 2; ++rt)
            #pragma unroll
            for (int c = 0; c < 4; ++c) racc[rt][c] = (f4){0.f, 0.f, 0.f, 0.f};
        __builtin_amdgcn_s_setprio(1);
        #pragma unroll 1
        for (int ks = 0; ks < 8; ++ks) {
            bf8 wf[4];
            #pragma unroll
            for (int c = 0; c < 4; ++c)
                wf[c] = *(const bf8*)(Wr + (size_t)(((ks * 16 + wc * 4 + c) * 64 + lane) * 8));
            #pragma unroll
            for (int rt = 0; rt < 2; ++rt) {
                bf8 sf = *(const bf8*)(&pool[sbase + (rt * 16 + lr) * 256 + ((ks * 32 + lg * 8) ^ swr)]);
                #pragma unroll
                for (int c = 0; c < 4; ++c)
                    racc[rt][c] = __builtin_amdgcn_mfma_f32_16x16x32_bf16(wf[c], sf, racc[rt][c], 0, 0, 0);
            }
        }
        __builtin_amdgcn_s_setprio(0);
        // Fused epilogue: q-partial = sum_h relu(racc + b) * wq[h], f32.
        // Lane holds hidden units (wc*4+c)*16+lg*4+i for batch rt*16+lr.
        float part[2] = {0.f, 0.f};
        #pragma unroll
        for (int c = 0; c < 4; ++c) {
            float4 bv = *(const float4*)(br + (wc * 4 + c) * 16 + lg * 4);
            float4 wv = *(const float4*)(wq + (wc * 4 + c) * 16 + lg * 4);
            #pragma unroll
            for (int rt = 0; rt < 2; ++rt) {
                part[rt] += fmaxf(racc[rt][c][0] + bv.x, 0.f) * wv.x
                          + fmaxf(racc[rt][c][1] + bv.y, 0.f) * wv.y
                          + fmaxf(racc[rt][c][2] + bv.z, 0.f) * wv.z
                          + fmaxf(racc[rt][c][3] + bv.w, 0.f) * wv.w;
            }
        }
        // Reduce over the 4 lg quads (lane bits 4,5); all lanes same-lr equal.
        #pragma unroll
        for (int rt = 0; rt < 2; ++rt) {
            part[rt] += __shfl_xor(part[rt], 16);
            part[rt] += __shfl_xor(part[rt], 32);
        }
        // One f32 partial per (net, batch, wc) into the dead inp region.
        if (lane < 16) {
            float* fs = (float*)pool;
            fs[(wr * 32 + lane) * 4 + wc]      = part[0];
            fs[(wr * 32 + 16 + lane) * 4 + wc] = part[1];
        }
        __syncthreads();
    }

    // ---- Final reduce: 64 threads sum the 4 wc partials. FP32 OUT ----
    if (t < 64) {
        int net = t >> 5, b = t & 31;
        const float* fs = (const float*)pool;
        float qv = net ? b8[0] : b6[0];
        #pragma unroll
        for (int p = 0; p < 4; ++p)
            qv += fs[(net * 32 + b) * 4 + p];
        out[net * B + wg * 32 + b] = qv;
    }
}

extern "C" void kernel_launch(void* const* d_in, const int* in_sizes, int n_in,
                              void* d_out, int out_size, void* d_ws, size_t ws_size,
                              hipStream_t stream) {
    const float* obs = (const float*)d_in[0];
    const float* ag  = (const float*)d_in[1];
    const float* g   = (const float*)d_in[2];
    const float* anc = (const float*)d_in[3];
    const float* act = (const float*)d_in[4];
    const float* w1  = (const float*)d_in[5];
    const float* b1  = (const float*)d_in[6];
    const float* w2  = (const float*)d_in[7];
    const float* b2  = (const float*)d_in[8];
    const float* w3  = (const float*)d_in[9];
    const float* b3  = (const float*)d_in[10];
    const float* w4  = (const float*)d_in[11];
    const float* b4  = (const float*)d_in[12];
    const float* w5  = (const float*)d_in[13];
    const float* b5  = (const float*)d_in[14];
    const float* w6  = (const float*)d_in[15];
    const float* b6  = (const float*)d_in[16];
    const float* w7  = (const float*)d_in[17];
    const float* b7  = (const float*)d_in[18];
    const float* w8  = (const float*)d_in[19];
    const float* b8  = (const float*)d_in[20];
    u16* ws    = (u16*)d_ws;
    float* out = (float*)d_out;
    int B = in_sizes[0] / 55;

    swz_all<<<36, 256, 0, stream>>>(w1, w3, w2, w4, w5, w7, ws);
    critic_kernel<<<(B + 31) / 32, 512, 0, stream>>>(obs, ag, g, anc, act,
                                                     b1, b2, b3, b4, b5, b7,
                                                     w6, b6, w8, b8, ws, out, B);
}

// Round 21
// 192.073 us; speedup vs baseline: 1.0875x; 1.0095x over previous
//
#include <hip/hip_runtime.h>
#include <hip/hip_bf16.h>

typedef unsigned short u16;
typedef unsigned int   u32;

using bf8 = __attribute__((ext_vector_type(8))) __bf16;
using f4  = __attribute__((ext_vector_type(4))) float;

__device__ __forceinline__ float b2f(u16 u) {
    union { u32 i; float f; } v; v.i = ((u32)u) << 16; return v.f;
}
__device__ __forceinline__ u16 f2b(float f) {
    union { float f; u32 i; } v; v.f = f;
    u32 x = v.i;
    x += 0x7fffu + ((x >> 16) & 1u);   // RNE
    return (u16)(x >> 16);
}
// Packed fp32x2 -> bf16x2 (low = first arg).
__device__ __forceinline__ u32 pk2(float lo, float hi) {
    union { __hip_bfloat162 h; u32 u; } v;
    v.h = __float22bfloat162_rn(make_float2(lo, hi));
    return v.u;
}

// ---------------------------------------------------------------------------
// Weight swizzle (verified layout — unchanged; frags used as A-operands):
// dst[((kt*16+ct)*64+lane)*8+j] = bf16(W[kt*32+(lane>>4)*8+j][ct*16+(lane&15)])
// ---------------------------------------------------------------------------
__global__ void swz_all(const float* __restrict__ w1, const float* __restrict__ w3,
                        const float* __restrict__ w2, const float* __restrict__ w4,
                        const float* __restrict__ w5, const float* __restrict__ w7,
                        u16* __restrict__ ws) {
    __shared__ u16 slab[32 * 270];
    int b = blockIdx.x, t = threadIdx.x;
    const float* src; u16* dst; int kmax, kt;
    if      (b <  2) { src = w1; dst = ws;          kmax = 54;  kt = b;      }
    else if (b <  4) { src = w3; dst = ws + 16384;  kmax = 54;  kt = b - 2;  }
    else if (b < 12) { src = w2; dst = ws + 32768;  kmax = 256; kt = b - 4;  }
    else if (b < 20) { src = w4; dst = ws + 98304;  kmax = 256; kt = b - 12; }
    else if (b < 28) { src = w5; dst = ws + 163840; kmax = 256; kt = b - 20; }
    else             { src = w7; dst = ws + 229376; kmax = 256; kt = b - 28; }

    #pragma unroll
    for (int it = 0; it < 8; ++it) {
        int flat = it * 1024 + t * 4;
        int row = flat >> 8, col = flat & 255;
        int k = kt * 32 + row;
        float4 v = make_float4(0.f, 0.f, 0.f, 0.f);
        if (k < kmax) v = *(const float4*)(src + k * 256 + col);
        u32* sp = (u32*)&slab[row * 270 + col];
        sp[0] = pk2(v.x, v.y);
        sp[1] = pk2(v.z, v.w);
    }
    __syncthreads();

    int lane = t & 63, wave = t >> 6, lr = lane & 15, kg = lane >> 4;
    #pragma unroll
    for (int i = 0; i < 4; ++i) {
        int ct = wave * 4 + i;
        u16 v[8];
        #pragma unroll
        for (int j = 0; j < 8; ++j)
            v[j] = slab[(kg * 8 + j) * 270 + ct * 16 + lr];
        uint4 o;
        o.x = (u32)v[0] | ((u32)v[1] << 16);
        o.y = (u32)v[2] | ((u32)v[3] << 16);
        o.z = (u32)v[4] | ((u32)v[5] << 16);
        o.w = (u32)v[6] | ((u32)v[7] << 16);
        *(uint4*)(dst + (size_t)(((kt * 16 + ct) * 64 + lane) * 8)) = o;
    }
}

// ---------------------------------------------------------------------------
// Fused critic (R15/R20 structure — session best, steady ~104 us).
// 512 thr / 8 waves, 2-D wave split: wr = batch-half / rho net, wc = 4
// column-tiles. unroll 1 weight loops (no spill), S1 early-evict to SB,
// fused final dot in rho epilogue.
//
// Gather divergence ladder: interleaved 4-part = +7us (R18, all bodies in
// every wave); contiguous 2-part = -3us vs R15 (R20, waves 0/2 uniform,
// wave 1 mixed). THIS round: part1 moved to threads 256..351 (waves 4,5)
// -> EVERY wave executes at most one branch body; waves 2,3,6,7 branch
// straight to the barrier. Last third of the divergence tax.
//
// LDS layout (u16), activation rows XOR-swizzled:
//   physical = row*stride + (logical_col ^ ((row&7)<<3))
//   inp: rows 0..95, stride 64  ([0, 6144))   (dead by rho -> f32 scratch)
//   h  : rows 0..95, stride 256 ([6144, 6144+24576)); S2 -> rows 32..63
//   SB : rows 0..31, stride 256 ([30720, 38912))  <- S1 early-evict region
// Total 77824 B -> 2 blocks/CU, 4 waves/SIMD.
// ---------------------------------------------------------------------------
#define H_OFF 6144
#define S2O   (32 * 256)
#define SBO   (H_OFF + 96 * 256)

__global__ __launch_bounds__(512) __attribute__((amdgpu_waves_per_eu(4, 4)))
void critic_kernel(
    const float* __restrict__ obs, const float* __restrict__ ag,
    const float* __restrict__ g,   const float* __restrict__ anchor,
    const float* __restrict__ act,
    const float* __restrict__ b1,  const float* __restrict__ b2,
    const float* __restrict__ b3,  const float* __restrict__ b4,
    const float* __restrict__ b5,  const float* __restrict__ b7,
    const float* __restrict__ w6,  const float* __restrict__ b6,
    const float* __restrict__ w8,  const float* __restrict__ b8,
    const u16* __restrict__ wsz, float* __restrict__ out, int B) {

    __shared__ u16 pool[SBO + 32 * 256];   // 38912 u16 = 77824 B

    const int t    = threadIdx.x;
    const int lane = t & 63;
    const int wave = t >> 6;     // 0..7
    const int wr   = wave >> 2;  // 0,1 : batch-lane half / rho net
    const int wc   = wave & 3;   // 0..3: 4 column-tiles
    const int lr   = lane & 15;
    const int lg   = lane >> 4;
    const int wg   = blockIdx.x;
    const int swr  = (lr & 7) << 3;   // row-XOR swizzle (h/inp rows are ..*16+lr)

    // ---- Gather: build pair inputs (96 rows x 54, pad to 64), swizzled.
    // part0 on t in [0,96) (waves 0,1); part1 on t in [256,352) (waves 4,5).
    // Every wave executes at most ONE branch body -> no exec-mask serialization.
    {
        const int O1[3] = {0, 0, 1}, O2[3] = {1, 2, 2};
        const int JA[3] = {3, 4, 6}, KA[3] = {5, 7, 8};
        int part = -1, rr = 0;
        if (t < 96)                  { part = 0; rr = t; }
        else if (t >= 256 && t < 352){ part = 1; rr = t - 256; }
        if (part >= 0) {
            int p = rr >> 5, bl = rr & 31;
            int b = wg * 32 + bl;
            int j = JA[p], k = KA[p];
            bool sel = (anchor[b * 9 + j] - anchor[b * 9 + k]) >= 0.0f;
            u16* row = &pool[rr * 64];
            const int sw = (rr & 7) << 3;
            const u16 ONE = 0x3F80;
            if (part == 0) {
                int bit2 = sel ? j : k;
                int oi = sel ? O1[p] : O2[p];
                row[0 ^ sw] = f2b(ag[b * 9 + p]);
                row[1 ^ sw] = f2b(ag[b * 9 + bit2]);
                row[2 ^ sw] = f2b(g[b * 9 + p]);
                row[3 ^ sw] = f2b(g[b * 9 + bit2]);
                for (int c = 0; c < 10; ++c) row[(4 + c) ^ sw] = f2b(obs[b * 55 + c]);
                row[14 ^ sw] = (oi == 0) ? ONE : 0;
                row[15 ^ sw] = (oi == 1) ? ONE : 0;
                row[16 ^ sw] = (oi == 2) ? ONE : 0;
                for (int c = 0; c < 15; ++c) row[(17 + c) ^ sw] = f2b(obs[b * 55 + 10 + 15 * oi + c]);
            } else {
                int oj = sel ? O2[p] : O1[p];
                row[32 ^ sw] = (oj == 0) ? ONE : 0;
                row[33 ^ sw] = (oj == 1) ? ONE : 0;
                row[34 ^ sw] = (oj == 2) ? ONE : 0;
                for (int c = 0; c < 15; ++c) row[(35 + c) ^ sw] = f2b(obs[b * 55 + 10 + 15 * oj + c]);
                for (int c = 0; c < 4; ++c)  row[(50 + c) ^ sw] = f2b(act[b * 4 + c]);
                for (int c = 54; c < 64; ++c) row[c ^ sw] = 0;
            }
        }
    }
    __syncthreads();

    u32 s2w[4][2];    // net1 pair-sums (brief: epilogue -> post-barrier write)

    // ---- Phi networks (net 0: w1/w2, net 1: w3/w4) ----
    for (int net = 0; net < 2; ++net) {
        const u16* Wl1 = wsz + (net ? 16384 : 0);
        const u16* Wl2 = wsz + 32768 + (net ? 65536 : 0);
        const float* bl1 = net ? b3 : b1;
        const float* bl2 = net ? b4 : b2;

        // Layer 1: A=W1^T frags, B=inp rows rt=2p+wr. D=(batch=lr, hid=lg*4+reg)
        f4 acc[3][4];
        #pragma unroll
        for (int p = 0; p < 3; ++p)
            #pragma unroll
            for (int c = 0; c < 4; ++c) acc[p][c] = (f4){0.f, 0.f, 0.f, 0.f};
        __builtin_amdgcn_s_setprio(1);
        #pragma unroll 1
        for (int kt = 0; kt < 2; ++kt) {
            bf8 wfr[4];
            #pragma unroll
            for (int c = 0; c < 4; ++c)
                wfr[c] = *(const bf8*)(Wl1 + (size_t)(((kt * 16 + wc * 4 + c) * 64 + lane) * 8));
            #pragma unroll
            for (int p = 0; p < 3; ++p) {
                bf8 xfr = *(const bf8*)(&pool[((2 * p + wr) * 16 + lr) * 64 + ((kt * 32 + lg * 8) ^ swr)]);
                #pragma unroll
                for (int c = 0; c < 4; ++c)
                    acc[p][c] = __builtin_amdgcn_mfma_f32_16x16x32_bf16(wfr[c], xfr, acc[p][c], 0, 0, 0);
            }
        }
        __builtin_amdgcn_s_setprio(0);
        #pragma unroll
        for (int c = 0; c < 4; ++c) {
            float4 bv = *(const float4*)(bl1 + (wc * 4 + c) * 16 + lg * 4);
            #pragma unroll
            for (int p = 0; p < 3; ++p) {
                uint2 w;
                w.x = pk2(fmaxf(acc[p][c][0] + bv.x, 0.f), fmaxf(acc[p][c][1] + bv.y, 0.f));
                w.y = pk2(fmaxf(acc[p][c][2] + bv.z, 0.f), fmaxf(acc[p][c][3] + bv.w, 0.f));
                *(uint2*)&pool[H_OFF + ((2 * p + wr) * 16 + lr) * 256 + ((((wc * 4 + c) * 16) + lg * 4) ^ swr)] = w;
            }
        }
        __syncthreads();

        // Layer 2: A=W2^T frags, B=h rows rt=2p+wr. Relu + in-register pair-sum.
        f4 acc2[3][4];
        #pragma unroll
        for (int p = 0; p < 3; ++p)
            #pragma unroll
            for (int c = 0; c < 4; ++c) acc2[p][c] = (f4){0.f, 0.f, 0.f, 0.f};
        __builtin_amdgcn_s_setprio(1);
        #pragma unroll 1
        for (int ks = 0; ks < 8; ++ks) {
            bf8 wfr[4];
            #pragma unroll
            for (int c = 0; c < 4; ++c)
                wfr[c] = *(const bf8*)(Wl2 + (size_t)(((ks * 16 + wc * 4 + c) * 64 + lane) * 8));
            #pragma unroll
            for (int p = 0; p < 3; ++p) {
                bf8 hfr = *(const bf8*)(&pool[H_OFF + ((2 * p + wr) * 16 + lr) * 256 + ((ks * 32 + lg * 8) ^ swr)]);
                #pragma unroll
                for (int c = 0; c < 4; ++c)
                    acc2[p][c] = __builtin_amdgcn_mfma_f32_16x16x32_bf16(wfr[c], hfr, acc2[p][c], 0, 0, 0);
            }
        }
        __builtin_amdgcn_s_setprio(0);
        #pragma unroll
        for (int c = 0; c < 4; ++c) {
            float4 bv = *(const float4*)(bl2 + (wc * 4 + c) * 16 + lg * 4);
            f4 sv = (f4){0.f, 0.f, 0.f, 0.f};
            #pragma unroll
            for (int p = 0; p < 3; ++p) {
                sv[0] += fmaxf(acc2[p][c][0] + bv.x, 0.f);
                sv[1] += fmaxf(acc2[p][c][1] + bv.y, 0.f);
                sv[2] += fmaxf(acc2[p][c][2] + bv.z, 0.f);
                sv[3] += fmaxf(acc2[p][c][3] + bv.w, 0.f);
            }
            if (net == 0) {
                // S1 early-evict: write straight to the dedicated SB region
                // (disjoint from h -> no race with other waves' h reads).
                uint2 w;
                w.x = pk2(sv[0], sv[1]);
                w.y = pk2(sv[2], sv[3]);
                *(uint2*)&pool[SBO + (wr * 16 + lr) * 256 + ((((wc * 4 + c) * 16) + lg * 4) ^ swr)] = w;
            } else {
                s2w[c][0] = pk2(sv[0], sv[1]);
                s2w[c][1] = pk2(sv[2], sv[3]);
            }
        }
        __syncthreads();  // h reads done before next net overwrites h / S2 write
    }

    // ---- Write S2 into dead h rows 32..63 (all h reads completed) ----
    #pragma unroll
    for (int c = 0; c < 4; ++c) {
        int base = H_OFF + S2O + (wr * 16 + lr) * 256 + ((((wc * 4 + c) * 16) + lg * 4) ^ swr);
        *(uint2*)&pool[base] = *(uint2*)&s2w[c][0];
    }
    __syncthreads();

    // ---- Rho hidden layer + FUSED final dot ----
    // wr picks the net (wr=0: S1@SB/W5/b5/w6, wr=1: S2/W7/b7/w8).
    {
        const u16* Wr    = wsz + (wr ? 229376 : 163840);
        const int sbase  = wr ? (H_OFF + S2O) : SBO;
        const float* br  = wr ? b7 : b5;
        const float* wq  = wr ? w8 : w6;
        f4 racc[2][4];
        #pragma unroll
        for (int rt = 0; rt < 2; ++rt)
            #pragma unroll
            for (int c = 0; c < 4; ++c) racc[rt][c] = (f4){0.f, 0.f, 0.f, 0.f};
        __builtin_amdgcn_s_setprio(1);
        #pragma unroll 1
        for (int ks = 0; ks < 8; ++ks) {
            bf8 wf[4];
            #pragma unroll
            for (int c = 0; c < 4; ++c)
                wf[c] = *(const bf8*)(Wr + (size_t)(((ks * 16 + wc * 4 + c) * 64 + lane) * 8));
            #pragma unroll
            for (int rt = 0; rt < 2; ++rt) {
                bf8 sf = *(const bf8*)(&pool[sbase + (rt * 16 + lr) * 256 + ((ks * 32 + lg * 8) ^ swr)]);
                #pragma unroll
                for (int c = 0; c < 4; ++c)
                    racc[rt][c] = __builtin_amdgcn_mfma_f32_16x16x32_bf16(wf[c], sf, racc[rt][c], 0, 0, 0);
            }
        }
        __builtin_amdgcn_s_setprio(0);
        // Fused epilogue: q-partial = sum_h relu(racc + b) * wq[h], f32.
        // Lane holds hidden units (wc*4+c)*16+lg*4+i for batch rt*16+lr.
        float part[2] = {0.f, 0.f};
        #pragma unroll
        for (int c = 0; c < 4; ++c) {
            float4 bv = *(const float4*)(br + (wc * 4 + c) * 16 + lg * 4);
            float4 wv = *(const float4*)(wq + (wc * 4 + c) * 16 + lg * 4);
            #pragma unroll
            for (int rt = 0; rt < 2; ++rt) {
                part[rt] += fmaxf(racc[rt][c][0] + bv.x, 0.f) * wv.x
                          + fmaxf(racc[rt][c][1] + bv.y, 0.f) * wv.y
                          + fmaxf(racc[rt][c][2] + bv.z, 0.f) * wv.z
                          + fmaxf(racc[rt][c][3] + bv.w, 0.f) * wv.w;
            }
        }
        // Reduce over the 4 lg quads (lane bits 4,5); all lanes same-lr equal.
        #pragma unroll
        for (int rt = 0; rt < 2; ++rt) {
            part[rt] += __shfl_xor(part[rt], 16);
            part[rt] += __shfl_xor(part[rt], 32);
        }
        // One f32 partial per (net, batch, wc) into the dead inp region.
        if (lane < 16) {
            float* fs = (float*)pool;
            fs[(wr * 32 + lane) * 4 + wc]      = part[0];
            fs[(wr * 32 + 16 + lane) * 4 + wc] = part[1];
        }
        __syncthreads();
    }

    // ---- Final reduce: 64 threads sum the 4 wc partials. FP32 OUT ----
    if (t < 64) {
        int net = t >> 5, b = t & 31;
        const float* fs = (const float*)pool;
        float qv = net ? b8[0] : b6[0];
        #pragma unroll
        for (int p = 0; p < 4; ++p)
            qv += fs[(net * 32 + b) * 4 + p];
        out[net * B + wg * 32 + b] = qv;
    }
}

extern "C" void kernel_launch(void* const* d_in, const int* in_sizes, int n_in,
                              void* d_out, int out_size, void* d_ws, size_t ws_size,
                              hipStream_t stream) {
    const float* obs = (const float*)d_in[0];
    const float* ag  = (const float*)d_in[1];
    const float* g   = (const float*)d_in[2];
    const float* anc = (const float*)d_in[3];
    const float* act = (const float*)d_in[4];
    const float* w1  = (const float*)d_in[5];
    const float* b1  = (const float*)d_in[6];
    const float* w2  = (const float*)d_in[7];
    const float* b2  = (const float*)d_in[8];
    const float* w3  = (const float*)d_in[9];
    const float* b3  = (const float*)d_in[10];
    const float* w4  = (const float*)d_in[11];
    const float* b4  = (const float*)d_in[12];
    const float* w5  = (const float*)d_in[13];
    const float* b5  = (const float*)d_in[14];
    const float* w6  = (const float*)d_in[15];
    const float* b6  = (const float*)d_in[16];
    const float* w7  = (const float*)d_in[17];
    const float* b7  = (const float*)d_in[18];
    const float* w8  = (const float*)d_in[19];
    const float* b8  = (const float*)d_in[20];
    u16* ws    = (u16*)d_ws;
    float* out = (float*)d_out;
    int B = in_sizes[0] / 55;

    swz_all<<<36, 256, 0, stream>>>(w1, w3, w2, w4, w5, w7, ws);
    critic_kernel<<<(B + 31) / 32, 512, 0, stream>>>(obs, ag, g, anc, act,
                                                     b1, b2, b3, b4, b5, b7,
                                                     w6, b6, w8, b8, ws, out, B);
}